// Round 1
// baseline (465.783 us; speedup 1.0000x reference)
//
#include <hip/hip_runtime.h>

// Max-unpool 2x2 stride 2, NHWC fp32.
// x: (16,128,128,256), pooled: (16,64,64,256), out: (16,128,128,256).
// out[argmax-of-window] = max(pooled, 0); elsewhere 0.
// tid = n<<18 | hp<<12 | wp<<6 | c4  (c4 = channel/4; C=256 -> 64 float4).
// All 4 window positions are coalesced 1KiB wave loads/stores (64 lanes x 16B).

__global__ __launch_bounds__(256) void unpool_kernel(
    const float4* __restrict__ x,
    const float4* __restrict__ pooled,
    float4* __restrict__ out,
    int total)
{
    int tid = blockIdx.x * blockDim.x + threadIdx.x;
    if (tid >= total) return;

    const int c4 = tid & 63;          // 64 float4 = 256 channels
    const int wp = (tid >> 6) & 63;   // 64 pooled cols
    const int hp = (tid >> 12) & 63;  // 64 pooled rows
    const int n  = tid >> 18;         // 16 images

    // float4-unit offsets in x/out (NHWC, H=W=128, C4=64).
    // row stride = 128*64 = 8192; col stride = 64.
    const int base = ((n * 128 + hp * 2) * 128 + wp * 2) * 64 + c4;

    const float4 v0 = x[base];               // (dh=0,dw=0)
    const float4 v1 = x[base + 64];          // (dh=0,dw=1)
    const float4 v2 = x[base + 8192];        // (dh=1,dw=0)
    const float4 v3 = x[base + 8192 + 64];   // (dh=1,dw=1)
    const float4 p  = pooled[tid];           // pooled flat index == tid

    float4 o0, o1, o2, o3;
    const float* a = reinterpret_cast<const float*>(&v0);
    const float* b = reinterpret_cast<const float*>(&v1);
    const float* c = reinterpret_cast<const float*>(&v2);
    const float* d = reinterpret_cast<const float*>(&v3);
    const float* pv = reinterpret_cast<const float*>(&p);
    float* w0 = reinterpret_cast<float*>(&o0);
    float* w1 = reinterpret_cast<float*>(&o1);
    float* w2 = reinterpret_cast<float*>(&o2);
    float* w3 = reinterpret_cast<float*>(&o3);

#pragma unroll
    for (int j = 0; j < 4; ++j) {
        // first-max tie-break in (dh,dw) row-major order -> strict '>' updates
        float best = a[j];
        int idx = 0;
        if (b[j] > best) { best = b[j]; idx = 1; }
        if (c[j] > best) { best = c[j]; idx = 2; }
        if (d[j] > best) { best = d[j]; idx = 3; }
        const float val = fmaxf(pv[j], 0.0f);  // scatter-max into zeros
        w0[j] = (idx == 0) ? val : 0.0f;
        w1[j] = (idx == 1) ? val : 0.0f;
        w2[j] = (idx == 2) ? val : 0.0f;
        w3[j] = (idx == 3) ? val : 0.0f;
    }

    out[base]             = o0;
    out[base + 64]        = o1;
    out[base + 8192]      = o2;
    out[base + 8192 + 64] = o3;
}

extern "C" void kernel_launch(void* const* d_in, const int* in_sizes, int n_in,
                              void* d_out, int out_size, void* d_ws, size_t ws_size,
                              hipStream_t stream) {
    const float4* x      = (const float4*)d_in[0];
    const float4* pooled = (const float4*)d_in[1];
    float4* out          = (float4*)d_out;

    // total threads = N * Hp * Wp * C4 = 16 * 64 * 64 * 64
    const int total = 16 * 64 * 64 * 64;
    const int block = 256;
    const int grid  = (total + block - 1) / block;  // 16384
    unpool_kernel<<<grid, block, 0, stream>>>(x, pooled, out, total);
}

// Round 3
// 454.953 us; speedup vs baseline: 1.0238x; 1.0238x over previous
//
#include <hip/hip_runtime.h>

// Max-unpool 2x2 stride 2, NHWC fp32.
// x: (16,128,128,256), pooled: (16,64,64,256), out: (16,128,128,256).
// out[argmax-of-window] = max(pooled, 0); elsewhere 0.
//
// R3: 2 windows (adjacent wp) per thread for 10 in-flight loads (MLP),
// nontemporal loads/stores (zero reuse; don't thrash L2/L3).
// Native ext_vector_type(4) so the nontemporal builtins accept the pointer.
// tid = n<<17 | hp<<11 | wq<<6 | c4 ; wq = wp/2 (32 pairs), c4 = channel/4.
// Every load/store is a coalesced 1KiB wave transaction (64 lanes x 16B).

typedef float f4 __attribute__((ext_vector_type(4)));

__device__ __forceinline__ void unpool_win(
    const f4 a, const f4 b, const f4 c, const f4 d, const f4 p,
    f4& o0, f4& o1, f4& o2, f4& o3)
{
#pragma unroll
    for (int j = 0; j < 4; ++j) {
        // first-max tie-break in (dh,dw) row-major order -> strict '>' updates
        float best = a[j];
        int idx = 0;
        if (b[j] > best) { best = b[j]; idx = 1; }
        if (c[j] > best) { best = c[j]; idx = 2; }
        if (d[j] > best) { best = d[j]; idx = 3; }
        const float val = fmaxf(p[j], 0.0f);  // scatter-max into zeros
        o0[j] = (idx == 0) ? val : 0.0f;
        o1[j] = (idx == 1) ? val : 0.0f;
        o2[j] = (idx == 2) ? val : 0.0f;
        o3[j] = (idx == 3) ? val : 0.0f;
    }
}

__global__ __launch_bounds__(256) void unpool_kernel(
    const f4* __restrict__ x,
    const f4* __restrict__ pooled,
    f4* __restrict__ out,
    int total)
{
    int tid = blockIdx.x * blockDim.x + threadIdx.x;
    if (tid >= total) return;

    const int c4 = tid & 63;          // 64 float4 = 256 channels
    const int wq = (tid >> 6) & 31;   // wp pair: wp = 2*wq, 2*wq+1
    const int hp = (tid >> 11) & 63;  // 64 pooled rows
    const int n  = tid >> 17;         // 16 images

    // float4-unit offsets (NHWC, H=W=128, C4=64): row stride 8192, col stride 64
    const int base = ((n * 128 + hp * 2) * 128 + wq * 4) * 64 + c4;
    const int pidx = ((n * 64 + hp) * 64 + wq * 2) * 64 + c4;

    // Issue all 10 loads up front (MLP), nontemporal (streaming, no reuse).
    const f4 v0 = __builtin_nontemporal_load(&x[base]);
    const f4 v1 = __builtin_nontemporal_load(&x[base + 64]);
    const f4 u0 = __builtin_nontemporal_load(&x[base + 128]);
    const f4 u1 = __builtin_nontemporal_load(&x[base + 192]);
    const f4 v2 = __builtin_nontemporal_load(&x[base + 8192]);
    const f4 v3 = __builtin_nontemporal_load(&x[base + 8192 + 64]);
    const f4 u2 = __builtin_nontemporal_load(&x[base + 8192 + 128]);
    const f4 u3 = __builtin_nontemporal_load(&x[base + 8192 + 192]);
    const f4 p0 = __builtin_nontemporal_load(&pooled[pidx]);
    const f4 p1 = __builtin_nontemporal_load(&pooled[pidx + 64]);

    f4 a0, a1, a2, a3, b0, b1, b2, b3;
    unpool_win(v0, v1, v2, v3, p0, a0, a1, a2, a3);
    unpool_win(u0, u1, u2, u3, p1, b0, b1, b2, b3);

    __builtin_nontemporal_store(a0, &out[base]);
    __builtin_nontemporal_store(a1, &out[base + 64]);
    __builtin_nontemporal_store(b0, &out[base + 128]);
    __builtin_nontemporal_store(b1, &out[base + 192]);
    __builtin_nontemporal_store(a2, &out[base + 8192]);
    __builtin_nontemporal_store(a3, &out[base + 8192 + 64]);
    __builtin_nontemporal_store(b2, &out[base + 8192 + 128]);
    __builtin_nontemporal_store(b3, &out[base + 8192 + 192]);
}

extern "C" void kernel_launch(void* const* d_in, const int* in_sizes, int n_in,
                              void* d_out, int out_size, void* d_ws, size_t ws_size,
                              hipStream_t stream) {
    const f4* x      = (const f4*)d_in[0];
    const f4* pooled = (const f4*)d_in[1];
    f4* out          = (f4*)d_out;

    // total threads = N * Hp * (Wp/2) * C4 = 16 * 64 * 32 * 64 = 2097152
    const int total = 16 * 64 * 32 * 64;
    const int block = 256;
    const int grid  = (total + block - 1) / block;  // 8192
    unpool_kernel<<<grid, block, 0, stream>>>(x, pooled, out, total);
}